// Round 7
// baseline (2032.296 us; speedup 1.0000x reference)
//
#include <hip/hip_runtime.h>
#include <math.h>

#define WIDTH 256
#define PTS 16             // points per GROUP (two groups per block)
#define NROW 80            // 5 chains * 16 points
#define CPLANE 20480       // halves per Z plane per group: 5v * 8kc * 64lane * 8

typedef _Float16 f16x8 __attribute__((ext_vector_type(8)));
typedef _Float16 f16x4 __attribute__((ext_vector_type(4)));
typedef __fp16   h16x2 __attribute__((ext_vector_type(2)));   // cvt_pkrtz return type
typedef float    f32x4 __attribute__((ext_vector_type(4)));

// fp32 -> fp16 hi + fp16 lo (2-split) -- used for WEIGHTS only (static, exact)
__device__ __forceinline__ void split2(float f, _Float16& h, _Float16& l) {
    h = (_Float16)f;
    l = (_Float16)(f - (float)h);
}
// z=tanh(u), s=1-z^2 = 4t/(1+t)^2 with t=exp(-2|u|): no cancellation in saturation.
// rcp via v_rcp_f32 (~1 ulp); verified absmax-neutral (r2/r6).
__device__ __forceinline__ void tanh_s(float u, float& z, float& s) {
    const float t = __expf(-2.0f * fabsf(u));
    const float r = __builtin_amdgcn_rcpf(1.0f + t);
    const float zm = (1.0f - t) * r;
    z = copysignf(zm, u);
    s = 4.0f * t * r * r;
}

// Pre-split w1..w5 into fp16 hi/lo, transposed + packed in MFMA A-frag order:
// wt2[(l*2+c)*65536 + ((jt*8+kc)*64 + lane)*8 + i] = comp_c(W[k][j]),
// j = jt*16 + (lane&15), k = kc*32 + (lane>>4)*8 + i.   (16x16x32 frag order)
__global__ void prep_w_kernel(const float* __restrict__ w1, const float* __restrict__ w2,
                              const float* __restrict__ w3, const float* __restrict__ w4,
                              const float* __restrict__ w5, _Float16* __restrict__ wt2)
{
    const int idx = blockIdx.x * blockDim.x + threadIdx.x;
    if (idx >= 5 * 16 * 8 * 64) return;
    const int lane = idx & 63;
    const int kc   = (idx >> 6) & 7;
    const int jt   = (idx >> 9) & 15;
    const int l    = idx >> 13;
    const float* Wsrc[5] = { w1, w2, w3, w4, w5 };
    const float* W = Wsrc[l];
    const int j  = jt * 16 + (lane & 15);
    const int k0 = kc * 32 + (lane >> 4) * 8;
    f16x8 vh, vl;
    #pragma unroll
    for (int i = 0; i < 8; ++i) {
        _Float16 h, lo;
        split2(W[(k0 + i) * WIDTH + j], h, lo);
        vh[i] = h; vl[i] = lo;
    }
    const int fo = ((jt * 8 + kc) * 64 + lane) * 8;
    *(f16x8*)(wt2 + (l * 2 + 0) * 65536 + fo) = vh;
    *(f16x8*)(wt2 + (l * 2 + 1) * 65536 + fo) = vl;
}

// Wave role-specialization: 512 threads = 8 waves, 1 block/CU (160 KiB LDS).
// Waves 0..3 = MFMA role (k-loops, full matrix pipe); waves 4..7 = VALU role
// (L0/EP/FDOT). Round-robin wave->SIMD assignment puts one wave of each role
// on every SIMD -> MFMA and VALU pipes co-issue (m114 regime) instead of the
// serial in-phase phases of the 256-thread version. Two 16-point groups per
// block; acc handed off MFMA->VALU via an 80 KiB LDS buffer (single-buffered;
// KL split in halves so read/write phases alternate hazard-free).
__global__ __launch_bounds__(512, 1)
void pde_mfma_kernel(const float* __restrict__ xyt,
                     const float* __restrict__ w0, const float* __restrict__ b0,
                     const float* __restrict__ b1, const float* __restrict__ b2,
                     const float* __restrict__ b3, const float* __restrict__ b4,
                     const float* __restrict__ b5,
                     const float* __restrict__ w6, const float* __restrict__ b6,
                     const _Float16* __restrict__ wt2,
                     float* __restrict__ out)
{
    __shared__ _Float16 Zsm[2 * CPLANE];    // ZA | ZB   (81920 B)
    __shared__ float    accbuf[20480];      // acc handoff (81920 B) -> 163840 total

    const int tid  = threadIdx.x;
    const int wid  = tid >> 6;
    const bool mf  = (wid < 4);            // MFMA role
    const int lane = tid & 63;
    const int t    = tid & 255;            // role-local thread id 0..255
    const int wv   = wid & 3;              // role-local wave id 0..3
    const int q    = lane >> 4;
    const int n15  = lane & 15;

    _Float16* const ZA = Zsm;
    _Float16* const ZB = Zsm + CPLANE;
    const long gp0A = (long)blockIdx.x * (2 * PTS);
    const long gp0B = gp0A + PTS;

    // exclusive-liveness across roles: MFMA accumulators / VALU loaded acc
    f32x4 acc[5][4];

    auto zero_acc = [&]() {
        #pragma unroll
        for (int v = 0; v < 5; ++v)
            #pragma unroll
            for (int Mt = 0; Mt < 4; ++Mt)
                acc[v][Mt] = (f32x4){0.f, 0.f, 0.f, 0.f};
    };

    // ---------------- layer 0: (3 -> 256), Taylor-mode, fp32 VALU ----------
    auto L0 = [&](_Float16* Zg, long gp0) {
        const int p = t & 15;
        const float x  = xyt[(gp0 + p) * 3 + 0];
        const float y  = xyt[(gp0 + p) * 3 + 1];
        const float tc = xyt[(gp0 + p) * 3 + 2];
        #pragma unroll
        for (int half = 0; half < 2; ++half) {
            const int jg = (t >> 4) + half * 16;   // 0..31, 8 features each
            f16x8 vh[5];
            #pragma unroll
            for (int c = 0; c < 8; ++c) {
                const int j = jg * 8 + c;
                const float wx = w0[0 * WIDTH + j];
                const float wy = w0[1 * WIDTH + j];
                const float wt = w0[2 * WIDTH + j];
                float zv, s;
                tanh_s(fmaf(x, wx, fmaf(y, wy, fmaf(tc, wt, b0[j]))), zv, s);
                const float vals[5] = { zv, s * wx, s * wy, s * wt,
                                        -2.0f * zv * s * (wx * wx + wy * wy) };
                #pragma unroll
                for (int v = 0; v < 5; ++v)
                    vh[v][c] = (_Float16)vals[v];
            }
            #pragma unroll
            for (int v = 0; v < 5; ++v) {
                const int off = ((v * 8 + (jg >> 2)) * 64 + (jg & 3) * 16 + p) * 8;
                *(f16x8*)&Zg[off] = vh[v];
            }
        }
    };

    // ---------------- half k-loop (kc0..kc0+3), weight-2-split 2 products ---
    auto KLhalf = [&](const _Float16* Wl, const _Float16* Zg, int kc0) {
        #pragma unroll
        for (int u = 0; u < 4; ++u) {
            const int kc = kc0 + u;
            f16x8 Ah[4], Al[4];
            #pragma unroll
            for (int Mt = 0; Mt < 4; ++Mt) {
                const int fo = (((wv * 4 + Mt) * 8 + kc) * 64 + lane) * 8;
                Ah[Mt] = *(const f16x8*)(Wl + fo);
                Al[Mt] = *(const f16x8*)(Wl + 65536 + fo);
            }
            #pragma unroll
            for (int v = 0; v < 5; ++v) {
                const int zo = ((v * 8 + kc) * 64 + lane) * 8;
                const f16x8 Bh = *(const f16x8*)&Zg[zo];
                #pragma unroll
                for (int Mt = 0; Mt < 4; ++Mt) {
                    f32x4 a = acc[v][Mt];
                    a = __builtin_amdgcn_mfma_f32_16x16x32_f16(Al[Mt], Bh, a, 0, 0, 0);
                    a = __builtin_amdgcn_mfma_f32_16x16x32_f16(Ah[Mt], Bh, a, 0, 0, 0);
                    acc[v][Mt] = a;
                }
            }
        }
    };

    // acc <-> LDS handoff; per-lane 16B contiguous -> conflict-free
    auto ACCW = [&]() {
        #pragma unroll
        for (int v = 0; v < 5; ++v)
            #pragma unroll
            for (int Mt = 0; Mt < 4; ++Mt)
                *(f32x4*)&accbuf[((v * 16 + wv * 4 + Mt) * 64 + lane) * 4] = acc[v][Mt];
    };
    auto RDACC = [&]() {
        #pragma unroll
        for (int v = 0; v < 5; ++v)
            #pragma unroll
            for (int Mt = 0; Mt < 4; ++Mt)
                acc[v][Mt] = *(const f32x4*)&accbuf[((v * 16 + wv * 4 + Mt) * 64 + lane) * 4];
    };

    // ---------------- epilogue (from acc regs) -> next-layer Z --------------
    auto EP = [&](int le, _Float16* Zg) {
        const float* Bb = (le == 0) ? b1 : (le == 1) ? b2 : (le == 2) ? b3
                        : (le == 3) ? b4 : b5;
        #pragma unroll
        for (int Mt = 0; Mt < 4; ++Mt) {
            const int jt = wv * 4 + Mt;
            float nv[5][4];
            #pragma unroll
            for (int reg = 0; reg < 4; ++reg) {
                const int j = jt * 16 + q * 4 + reg;
                float zv, s;
                tanh_s(acc[0][Mt][reg] + Bb[j], zv, s);
                const float u1 = acc[1][Mt][reg];
                const float u2 = acc[2][Mt][reg];
                nv[0][reg] = zv;
                nv[1][reg] = s * u1;
                nv[2][reg] = s * u2;
                nv[3][reg] = s * acc[3][Mt][reg];
                nv[4][reg] = fmaf(-2.0f * zv * s, fmaf(u1, u1, u2 * u2),
                                  s * acc[4][Mt][reg]);
            }
            const int j0 = jt * 16 + q * 4;
            const int off0 = ((j0 >> 5) * 64 + ((j0 >> 3) & 3) * 16 + n15) * 8 + (j0 & 7);
            #pragma unroll
            for (int v = 0; v < 5; ++v) {
                const h16x2 h01 = __builtin_amdgcn_cvt_pkrtz(nv[v][0], nv[v][1]);
                const h16x2 h23 = __builtin_amdgcn_cvt_pkrtz(nv[v][2], nv[v][3]);
                *(f16x4*)&Zg[v * 4096 + off0] =
                    (f16x4){ (_Float16)h01[0], (_Float16)h01[1],
                             (_Float16)h23[0], (_Float16)h23[1] };
            }
        }
    };

    // ---------------- final layer: (256 -> 1) dot products ------------------
    auto FDOT = [&](const _Float16* Zg) -> float {
        float partial = 0.f;
        if (t < 2 * NROW) {
            const int n  = t >> 1;        // row 0..79
            const int hf = t & 1;
            const int v = n >> 4, p = n & 15;
            for (int kk = hf * 128; kk < hf * 128 + 128; kk += 8) {
                const int off = ((v * 8 + (kk >> 5)) * 64 + ((kk >> 3) & 3) * 16 + p) * 8;
                const f16x8 zh = *(const f16x8*)&Zg[off];
                #pragma unroll
                for (int i = 0; i < 8; ++i)
                    partial = fmaf((float)zh[i], w6[kk + i], partial);
            }
        }
        return partial;
    };
    auto RES = [&](const float* tot, long gp0) {
        if (t < PTS) {
            const int p = t;
            const float h   = tot[0 * 16 + p] + b6[0];
            const float hx  = tot[1 * 16 + p];
            const float hy  = tot[2 * 16 + p];
            const float ht  = tot[3 * 16 + p];
            const float lap = tot[4 * 16 + p];
            const float x  = xyt[(gp0 + p) * 3 + 0];
            const float y  = xyt[(gp0 + p) * 3 + 1];
            const float tc = xyt[(gp0 + p) * 3 + 2];
            const float pi = 3.14159265358979323846f;
            const float f = sinf(pi * x) * sinf(pi * y) * expf(-tc);
            out[gp0 + p] = ht - 0.5f * (fmaf(h, lap, fmaf(hx, hx, hy * hy))) - f;
        }
    };

    // ---------------- role-split schedule -----------------------------------
    if (!mf) L0(ZA, gp0A);
    __syncthreads();

    #pragma unroll 1
    for (int l = 0; l < 5; ++l) {
        const _Float16* Wl = wt2 + l * 2 * 65536;
        // 1a: MFMA: KLA(l) half 1 | VALU: L0B (l=0) or load accB(l-1)
        if (mf) { zero_acc(); KLhalf(Wl, ZA, 0); }
        else if (l == 0) L0(ZB, gp0B);
        else RDACC();
        __syncthreads();
        // 1b: MFMA: KLA(l) half 2 + accA(l)->LDS | VALU: EPB(l-1) -> ZB(l)
        if (mf) { KLhalf(Wl, ZA, 4); ACCW(); }
        else if (l > 0) EP(l - 1, ZB);
        __syncthreads();
        // 2a: MFMA: KLB(l) half 1 | VALU: load accA(l)
        if (mf) { zero_acc(); KLhalf(Wl, ZB, 0); }
        else RDACC();
        __syncthreads();
        // 2b: MFMA: KLB(l) half 2 + accB(l)->LDS | VALU: EPA(l) -> ZA(l+1)
        if (mf) { KLhalf(Wl, ZB, 4); ACCW(); }
        else EP(l, ZA);
        __syncthreads();
    }

    // ---------------- tail ---------------------------------------------------
    float part = 0.f;
    if (!mf) RDACC();                       // accB(4)
    else part = FDOT(ZA);                   // ZA final (EPA(4) in 2b, barrier'd)
    __syncthreads();
    float* const redfA = accbuf;            // handoff reads done -> alias safe
    float* const redfB = accbuf + 512;
    if (!mf) EP(4, ZB);                     // -> ZB final
    else if (t < 2 * NROW) redfA[(t & 1) * NROW + (t >> 1)] = part;
    __syncthreads();
    if (mf) part = FDOT(ZB);
    else if (t < NROW) redfA[2 * NROW + t] = redfA[t] + redfA[NROW + t];
    __syncthreads();
    if (mf) { if (t < 2 * NROW) redfB[(t & 1) * NROW + (t >> 1)] = part; }
    else RES(redfA + 2 * NROW, gp0A);
    __syncthreads();
    if (!mf && t < NROW) redfB[2 * NROW + t] = redfB[t] + redfB[NROW + t];
    __syncthreads();
    if (!mf) RES(redfB + 2 * NROW, gp0B);
}

extern "C" void kernel_launch(void* const* d_in, const int* in_sizes, int n_in,
                              void* d_out, int out_size, void* d_ws, size_t ws_size,
                              hipStream_t stream) {
    const float* xyt = (const float*)d_in[0];
    const float* w0  = (const float*)d_in[1];
    const float* b0  = (const float*)d_in[2];
    const float* w1  = (const float*)d_in[3];
    const float* b1  = (const float*)d_in[4];
    const float* w2  = (const float*)d_in[5];
    const float* b2  = (const float*)d_in[6];
    const float* w3  = (const float*)d_in[7];
    const float* b3  = (const float*)d_in[8];
    const float* w4  = (const float*)d_in[9];
    const float* b4  = (const float*)d_in[10];
    const float* w5  = (const float*)d_in[11];
    const float* b5  = (const float*)d_in[12];
    const float* w6  = (const float*)d_in[13];
    const float* b6  = (const float*)d_in[14];
    float* out = (float*)d_out;
    _Float16* wt2 = (_Float16*)d_ws;    // needs 5*2*65536*2 = 1,310,720 B

    prep_w_kernel<<<160, 256, 0, stream>>>(w1, w2, w3, w4, w5, wt2);

    const int npts = in_sizes[0] / 3;   // 131072
    dim3 grid(npts / (2 * PTS));        // 4096 blocks x 512 threads (2 groups)
    dim3 block(512);
    pde_mfma_kernel<<<grid, block, 0, stream>>>(xyt, w0, b0, b1, b2, b3, b4, b5,
                                                w6, b6, wt2, out);
}

// Round 8
// 643.151 us; speedup vs baseline: 3.1599x; 3.1599x over previous
//
#include <hip/hip_runtime.h>
#include <math.h>

#define WIDTH 256
#define PTS 16
#define NROW 80            // 5 chains * 16 points
#define CPLANE 20480       // halves per Z plane: 5v * 8kc * 64lane * 8

typedef _Float16 f16x8 __attribute__((ext_vector_type(8)));
typedef _Float16 f16x4 __attribute__((ext_vector_type(4)));
typedef __fp16   h16x2 __attribute__((ext_vector_type(2)));   // cvt_pkrtz return type
typedef float    f32x4 __attribute__((ext_vector_type(4)));

// fp32 -> fp16 hi + fp16 lo (2-split) -- used for WEIGHTS only (static, exact)
__device__ __forceinline__ void split2(float f, _Float16& h, _Float16& l) {
    h = (_Float16)f;
    l = (_Float16)(f - (float)h);
}
// z=tanh(u), s=1-z^2 = 4t/(1+t)^2 with t=exp(-2|u|): no cancellation in saturation.
// rcp via v_rcp_f32 (~1 ulp); verified absmax-neutral (r2/r6).
__device__ __forceinline__ void tanh_s(float u, float& z, float& s) {
    const float t = __expf(-2.0f * fabsf(u));
    const float r = __builtin_amdgcn_rcpf(1.0f + t);
    const float zm = (1.0f - t) * r;
    z = copysignf(zm, u);
    s = 4.0f * t * r * r;
}

// Pre-split w1..w5 into fp16 hi/lo, transposed + packed in MFMA A-frag order:
// wt2[(l*2+c)*65536 + ((jt*8+kc)*64 + lane)*8 + i] = comp_c(W[k][j]),
// j = jt*16 + (lane&15), k = kc*32 + (lane>>4)*8 + i.   (16x16x32 frag order)
__global__ void prep_w_kernel(const float* __restrict__ w1, const float* __restrict__ w2,
                              const float* __restrict__ w3, const float* __restrict__ w4,
                              const float* __restrict__ w5, _Float16* __restrict__ wt2)
{
    const int idx = blockIdx.x * blockDim.x + threadIdx.x;
    if (idx >= 5 * 16 * 8 * 64) return;
    const int lane = idx & 63;
    const int kc   = (idx >> 6) & 7;
    const int jt   = (idx >> 9) & 15;
    const int l    = idx >> 13;
    const float* Wsrc[5] = { w1, w2, w3, w4, w5 };
    const float* W = Wsrc[l];
    const int j  = jt * 16 + (lane & 15);
    const int k0 = kc * 32 + (lane >> 4) * 8;
    f16x8 vh, vl;
    #pragma unroll
    for (int i = 0; i < 8; ++i) {
        _Float16 h, lo;
        split2(W[(k0 + i) * WIDTH + j], h, lo);
        vh[i] = h; vl[i] = lo;
    }
    const int fo = ((jt * 8 + kc) * 64 + lane) * 8;
    *(f16x8*)(wt2 + (l * 2 + 0) * 65536 + fo) = vh;
    *(f16x8*)(wt2 + (l * 2 + 1) * 65536 + fo) = vl;
}

// r6 structure (2+ blocks/CU, serial phases), with per-chain precision tiering:
// v=0 (value chain; its error compounds via s=1-z^2 into every chain) keeps the
// weight-2-split 2-product MFMA; v=1..4 (derivative chains; error gain ~1/layer)
// use a single Ah*Bh product. MFMA floor drops 414 -> 248 us.
__global__ __launch_bounds__(256, 2)
void pde_mfma_kernel(const float* __restrict__ xyt,
                     const float* __restrict__ w0, const float* __restrict__ b0,
                     const float* __restrict__ b1, const float* __restrict__ b2,
                     const float* __restrict__ b3, const float* __restrict__ b4,
                     const float* __restrict__ b5,
                     const float* __restrict__ w6, const float* __restrict__ b6,
                     const _Float16* __restrict__ wt2,
                     float* __restrict__ out)
{
    // Zs[((v*8 + kc)*64 + lane)*8 + i] = Z[point n = lane&15, k = kc*32 + (lane>>4)*8 + i]
    __shared__ _Float16 Zs[CPLANE];   // 40960 B
    float* redf = (float*)Zs;         // aliased reduction scratch (after last Z read)

    const int tid = threadIdx.x;
    const long gp0 = (long)blockIdx.x * PTS;

    // ---------------- layer 0: (3 -> 256), Taylor-mode, fp32 VALU ----------
    {
        const int p = tid & 15;
        const float x = xyt[(gp0 + p) * 3 + 0];
        const float y = xyt[(gp0 + p) * 3 + 1];
        const float t = xyt[(gp0 + p) * 3 + 2];
        #pragma unroll
        for (int half = 0; half < 2; ++half) {
            const int jg = (tid >> 4) + half * 16;   // 0..31, 8 features each
            f16x8 vh[5];
            #pragma unroll
            for (int c = 0; c < 8; ++c) {
                const int j = jg * 8 + c;
                const float wx = w0[0 * WIDTH + j];
                const float wy = w0[1 * WIDTH + j];
                const float wt = w0[2 * WIDTH + j];
                float zv, s;
                tanh_s(fmaf(x, wx, fmaf(y, wy, fmaf(t, wt, b0[j]))), zv, s);
                const float vals[5] = { zv, s * wx, s * wy, s * wt,
                                        -2.0f * zv * s * (wx * wx + wy * wy) };
                #pragma unroll
                for (int v = 0; v < 5; ++v)
                    vh[v][c] = (_Float16)vals[v];
            }
            // j block jg*8..+7: kc = jg>>2, q' = jg&3, i = c
            #pragma unroll
            for (int v = 0; v < 5; ++v) {
                const int off = ((v * 8 + (jg >> 2)) * 64 + (jg & 3) * 16 + p) * 8;
                *(f16x8*)&Zs[off] = vh[v];
            }
        }
    }
    __syncthreads();

    // ------- hidden layers 1..5: MFMA fp16; v=0: 2 products, v>=1: 1 -------
    const float* Bsl[5] = { b1, b2, b3, b4, b5 };
    const int lane = tid & 63;
    const int wv   = tid >> 6;       // wave 0..3 -> M-tiles 4w..4w+3
    const int q    = lane >> 4;
    const int n15  = lane & 15;

    for (int l = 0; l < 5; ++l) {
        const _Float16* Wl = wt2 + l * 2 * 65536;
        f32x4 acc[5][4];
        #pragma unroll
        for (int v = 0; v < 5; ++v)
            #pragma unroll
            for (int Mt = 0; Mt < 4; ++Mt)
                acc[v][Mt] = (f32x4){0.f, 0.f, 0.f, 0.f};

        #pragma unroll 2
        for (int kc = 0; kc < 8; ++kc) {
            f16x8 Ah[4], Al[4];
            #pragma unroll
            for (int Mt = 0; Mt < 4; ++Mt) {
                const int fo = (((wv * 4 + Mt) * 8 + kc) * 64 + lane) * 8;
                Ah[Mt] = *(const f16x8*)(Wl + fo);
                Al[Mt] = *(const f16x8*)(Wl + 65536 + fo);
            }
            #pragma unroll
            for (int v = 0; v < 5; ++v) {
                const int zo = ((v * 8 + kc) * 64 + lane) * 8;
                const f16x8 Bh = *(const f16x8*)&Zs[zo];
                #pragma unroll
                for (int Mt = 0; Mt < 4; ++Mt) {
                    f32x4 a = acc[v][Mt];
                    if (v == 0)   // value chain: weight-lo correction kept
                        a = __builtin_amdgcn_mfma_f32_16x16x32_f16(Al[Mt], Bh, a, 0, 0, 0);
                    a = __builtin_amdgcn_mfma_f32_16x16x32_f16(Ah[Mt], Bh, a, 0, 0, 0);
                    acc[v][Mt] = a;
                }
            }
        }
        __syncthreads();   // all Zs reads done before overwrite

        // epilogue: lane holds (j = jt*16 + q*4 + reg, p = n15), all 5 chains
        const float* Bb = Bsl[l];
        #pragma unroll
        for (int Mt = 0; Mt < 4; ++Mt) {
            const int jt = wv * 4 + Mt;
            float nv[5][4];
            #pragma unroll
            for (int reg = 0; reg < 4; ++reg) {
                const int j = jt * 16 + q * 4 + reg;
                float zv, s;
                tanh_s(acc[0][Mt][reg] + Bb[j], zv, s);
                const float u1 = acc[1][Mt][reg];
                const float u2 = acc[2][Mt][reg];
                nv[0][reg] = zv;
                nv[1][reg] = s * u1;
                nv[2][reg] = s * u2;
                nv[3][reg] = s * acc[3][Mt][reg];
                nv[4][reg] = fmaf(-2.0f * zv * s, fmaf(u1, u1, u2 * u2),
                                  s * acc[4][Mt][reg]);
            }
            // j0 = jt*16 + q*4 -> kc' = j0>>5, q'' = (j0>>3)&3, i0 = j0&7
            const int j0 = jt * 16 + q * 4;
            const int off0 = ((j0 >> 5) * 64 + ((j0 >> 3) & 3) * 16 + n15) * 8 + (j0 & 7);
            #pragma unroll
            for (int v = 0; v < 5; ++v) {
                const h16x2 h01 = __builtin_amdgcn_cvt_pkrtz(nv[v][0], nv[v][1]);
                const h16x2 h23 = __builtin_amdgcn_cvt_pkrtz(nv[v][2], nv[v][3]);
                *(f16x4*)&Zs[v * 4096 + off0] =
                    (f16x4){ (_Float16)h01[0], (_Float16)h01[1],
                             (_Float16)h23[0], (_Float16)h23[1] };
            }
        }
        __syncthreads();
    }

    // ---------------- final layer: (256 -> 1) dot products ------------------
    // 80 rows x 2 halves of 128 features; 160 active threads.
    float partial = 0.f;
    const int n    = tid >> 1;        // row 0..79 (valid if tid < 160)
    const int half = tid & 1;
    if (tid < 2 * NROW) {
        const int v = n >> 4, p = n & 15;
        for (int kk = half * 128; kk < half * 128 + 128; kk += 8) {
            const int off = ((v * 8 + (kk >> 5)) * 64 + ((kk >> 3) & 3) * 16 + p) * 8;
            const f16x8 zh = *(const f16x8*)&Zs[off];
            #pragma unroll
            for (int i = 0; i < 8; ++i)
                partial = fmaf((float)zh[i], w6[kk + i], partial);
        }
    }
    __syncthreads();                 // all reads of Zs done before aliasing
    if (tid < 2 * NROW) redf[half * NROW + n] = partial;
    __syncthreads();
    if (tid < NROW) redf[2 * NROW + tid] = redf[tid] + redf[NROW + tid];
    __syncthreads();

    // ---------------- residual ----------------
    if (tid < PTS) {
        const int p = tid;
        const float* tot = redf + 2 * NROW;
        const float h   = tot[0 * 16 + p] + b6[0];
        const float hx  = tot[1 * 16 + p];
        const float hy  = tot[2 * 16 + p];
        const float ht  = tot[3 * 16 + p];
        const float lap = tot[4 * 16 + p];
        const float x = xyt[(gp0 + p) * 3 + 0];
        const float y = xyt[(gp0 + p) * 3 + 1];
        const float t = xyt[(gp0 + p) * 3 + 2];
        const float pi = 3.14159265358979323846f;
        const float f = sinf(pi * x) * sinf(pi * y) * expf(-t);
        out[gp0 + p] = ht - 0.5f * (fmaf(h, lap, fmaf(hx, hx, hy * hy))) - f;
    }
}

extern "C" void kernel_launch(void* const* d_in, const int* in_sizes, int n_in,
                              void* d_out, int out_size, void* d_ws, size_t ws_size,
                              hipStream_t stream) {
    const float* xyt = (const float*)d_in[0];
    const float* w0  = (const float*)d_in[1];
    const float* b0  = (const float*)d_in[2];
    const float* w1  = (const float*)d_in[3];
    const float* b1  = (const float*)d_in[4];
    const float* w2  = (const float*)d_in[5];
    const float* b2  = (const float*)d_in[6];
    const float* w3  = (const float*)d_in[7];
    const float* b3  = (const float*)d_in[8];
    const float* w4  = (const float*)d_in[9];
    const float* b4  = (const float*)d_in[10];
    const float* w5  = (const float*)d_in[11];
    const float* b5  = (const float*)d_in[12];
    const float* w6  = (const float*)d_in[13];
    const float* b6  = (const float*)d_in[14];
    float* out = (float*)d_out;
    _Float16* wt2 = (_Float16*)d_ws;    // needs 5*2*65536*2 = 1,310,720 B

    prep_w_kernel<<<160, 256, 0, stream>>>(w1, w2, w3, w4, w5, wt2);

    const int npts = in_sizes[0] / 3;   // 131072
    dim3 grid(npts / PTS);              // 8192
    dim3 block(256);
    pde_mfma_kernel<<<grid, block, 0, stream>>>(xyt, w0, b0, b1, b2, b3, b4, b5,
                                                w6, b6, wt2, out);
}